// Round 5
// baseline (1101.005 us; speedup 1.0000x reference)
//
#include <hip/hip_runtime.h>

#define NROWS   131072
#define INDIM   512
#define HIDD    128
#define KCB     256
#define RPB     128   // rows per block
#define THREADS 512

// ---- d_ws layout (32-bit word offsets) ----
#define OFF_A     0u        // 3*128*256 = 98304 : folded codebook matrices
#define OFF_CV    98304u    // 3*256            : folded bias terms
#define OFF_LOG   99072u    // 131072           : logits
#define OFF_HIST  230144u   // 65536            : top-16-bit histogram
#define OFF_META  295680u   // 16               : cntA, cntB, p, Sp
#define OFF_LISTA 295696u   // 64*2
#define OFF_LISTB 295824u   // 2048*2
#define LISTB_CAP 2048u

// T tile index with XOR row-swizzle: kills the 16-way bank conflict on the
// float4 column-stores (rounds 1-4: constant 9.4e6 conflict cycles). XOR on
// row bits 2..4 keeps float4 contiguity; reads use the same (c,k) dimension
// so write/read swizzles match; per-k uniform XOR keeps reads broadcast.
#define TIDX(c, r) ((c) * RPB + ((r) ^ ((((c) >> 2) & 7) << 2)))

__device__ __forceinline__ unsigned order_key(float f) {
    unsigned u = __float_as_uint(f);
    return u ^ ((u & 0x80000000u) ? 0xFFFFFFFFu : 0x80000000u);
}

// ---------------------------------------------------------------------------
// Precompute A_c[j][k] = (1/||cb_k||) * sum_d W_c[j][d]*cb_k[d]
//            cv_c[k]   = (1/||cb_k||) * sum_d  b_c[d]*cb_k[d]
// Also zeros hist+meta (stream-ordered before vq_main).
// ---------------------------------------------------------------------------
__global__ __launch_bounds__(256) void vq_precompute(
    const float* __restrict__ Wm, const float* __restrict__ bm,
    const float* __restrict__ Wt, const float* __restrict__ bt,
    const float* __restrict__ Wp, const float* __restrict__ bp,
    const float* __restrict__ cbm, const float* __restrict__ cbt, const float* __restrict__ cbp,
    float* __restrict__ A, float* __restrict__ cv, unsigned* __restrict__ hist)
{
    for (unsigned i = blockIdx.x * 256u + threadIdx.x; i < 65536u + 16u; i += 24u * 256u)
        hist[i] = 0u;

    const int c  = blockIdx.x >> 3;
    const int jg = (blockIdx.x & 7) * 16;
    const float* W  = (c == 0) ? Wm  : (c == 1) ? Wt  : Wp;
    const float* bb = (c == 0) ? bm  : (c == 1) ? bt  : bp;
    const float* cb = (c == 0) ? cbm : (c == 1) ? cbt : cbp;
    const int k = threadIdx.x;
    const float4* cbr = (const float4*)(cb + (size_t)k * HIDD);
    float s = 0.f;
    for (int d = 0; d < HIDD / 4; ++d) {
        float4 x = cbr[d];
        s += x.x * x.x + x.y * x.y + x.z * x.z + x.w * x.w;
    }
    const float rn = 1.f / fmaxf(sqrtf(s), 1e-12f);
    for (int j = jg; j < jg + 16; ++j) {
        const float4* wr = (const float4*)(W + (size_t)j * HIDD);
        float acc = 0.f;
        for (int d = 0; d < HIDD / 4; ++d) {
            float4 x = cbr[d]; float4 w = wr[d];
            acc += x.x * w.x + x.y * w.y + x.z * w.z + x.w * w.w;
        }
        A[((size_t)c * HIDD + j) * KCB + k] = acc * rn;
    }
    if (jg == 0) {
        const float4* br = (const float4*)bb;
        float acc = 0.f;
        for (int d = 0; d < HIDD / 4; ++d) {
            float4 x = cbr[d]; float4 w = br[d];
            acc += x.x * w.x + x.y * w.y + x.z * w.z + x.w * w.w;
        }
        cv[(size_t)c * KCB + k] = acc * rn;
    }
}

// ---------------------------------------------------------------------------
// Main fused kernel: 128 rows/block, 512 threads (tx=t&15 cols, ty=t>>4 gives
// 32 row-groups x 4 rows). LDS 80 KiB (T 64K + S 16K) -> 2 blocks/CU =
// 16 waves/CU = 4 waves/SIMD (round-4 ran 2 waves/SIMD and stalled on memory
// latency at VALUBusy 56%). Per-thread tiles 4x8 keep VGPR ~90 < 128 so the
// 16-wave occupancy is register-feasible. B-operands (W1,W2,A) read directly
// from global (L1/L2-resident, wave-uniform across ty); only h0 chunks and
// the H^T tile live in LDS.
// ---------------------------------------------------------------------------
__global__ __launch_bounds__(THREADS) void vq_main(
    const float* __restrict__ h0, const float* __restrict__ W1, const float* __restrict__ bias1,
    const float* __restrict__ W2, const float* __restrict__ bias2,
    const float* __restrict__ Amat, const float* __restrict__ cv, const float* __restrict__ wsv,
    int* __restrict__ codes, float* __restrict__ logits, unsigned* __restrict__ hist)
{
    __shared__ float T[HIDD * RPB];  // 64 KiB, [k][row] with XOR row-swizzle
    __shared__ float S[4096];        // 16 KiB: 2 x 2048 h0^T chunk buffers / wsv

    const int t  = threadIdx.x;
    const int tx = t & 15;
    const int ty = t >> 4;           // 0..31, rows 4*ty .. 4*ty+3
    const int row0 = blockIdx.x * RPB;

    // ---------------- phase 1: a1 = relu(h0 @ W1 + b1) -> T (transposed)
    {
        float acc[4][8] = {};
        const int srow = t >> 2;            // 0..127
        const int sq   = (t & 3) * 4;       // k-offset 0,4,8,12 within chunk
        const float* hp = h0 + (size_t)(row0 + srow) * INDIM + sq;
        float4 ha = *(const float4*)hp;
        for (int kc = 0; kc < INDIM; kc += 16) {
            float* Sb = S + ((kc >> 4) & 1) * 2048;
            Sb[(sq + 0) * RPB + srow] = ha.x;
            Sb[(sq + 1) * RPB + srow] = ha.y;
            Sb[(sq + 2) * RPB + srow] = ha.z;
            Sb[(sq + 3) * RPB + srow] = ha.w;
            __syncthreads();
            if (kc + 16 < INDIM)             // prefetch next chunk under the FMAs
                ha = *(const float4*)(hp + kc + 16);
            const float* Wb = W1 + (size_t)kc * HIDD + 4 * tx;
            #pragma unroll 4
            for (int k = 0; k < 16; ++k) {
                float4 a0 = *(const float4*)&Sb[k * RPB + 4 * ty];
                float4 b0 = *(const float4*)(Wb + k * HIDD);
                float4 b1 = *(const float4*)(Wb + k * HIDD + 64);
                float aa[4] = {a0.x, a0.y, a0.z, a0.w};
                float bb[8] = {b0.x, b0.y, b0.z, b0.w, b1.x, b1.y, b1.z, b1.w};
                #pragma unroll
                for (int r = 0; r < 4; ++r)
                    #pragma unroll
                    for (int j = 0; j < 8; ++j)
                        acc[r][j] = fmaf(aa[r], bb[j], acc[r][j]);
            }
        }
        float4 bv0 = *(const float4*)&bias1[4 * tx];
        float4 bv1 = *(const float4*)&bias1[4 * tx + 64];
        float ba[8] = {bv0.x, bv0.y, bv0.z, bv0.w, bv1.x, bv1.y, bv1.z, bv1.w};
        #pragma unroll
        for (int i = 0; i < 2; ++i)
            #pragma unroll
            for (int j = 0; j < 4; ++j) {
                const int c = 4 * tx + 64 * i + j;
                float4 v;
                v.x = fmaxf(acc[0][i * 4 + j] + ba[i * 4 + j], 0.f);
                v.y = fmaxf(acc[1][i * 4 + j] + ba[i * 4 + j], 0.f);
                v.z = fmaxf(acc[2][i * 4 + j] + ba[i * 4 + j], 0.f);
                v.w = fmaxf(acc[3][i * 4 + j] + ba[i * 4 + j], 0.f);
                *(float4*)&T[TIDX(c, 4 * ty)] = v;
            }
    }
    __syncthreads();

    // ---------------- phase 2: H = relu(a1 @ W2 + b2), overwrite T with H^T
    {
        float acc[4][8] = {};
        const float* Wb = W2 + 4 * tx;
        #pragma unroll 4
        for (int k = 0; k < HIDD; ++k) {
            float4 a0 = *(const float4*)&T[TIDX(k, 4 * ty)];
            float4 b0 = *(const float4*)(Wb + k * HIDD);
            float4 b1 = *(const float4*)(Wb + k * HIDD + 64);
            float aa[4] = {a0.x, a0.y, a0.z, a0.w};
            float bb[8] = {b0.x, b0.y, b0.z, b0.w, b1.x, b1.y, b1.z, b1.w};
            #pragma unroll
            for (int r = 0; r < 4; ++r)
                #pragma unroll
                for (int j = 0; j < 8; ++j)
                    acc[r][j] = fmaf(aa[r], bb[j], acc[r][j]);
        }
        __syncthreads();                    // all T(a1) reads done before overwrite
        float4 bv0 = *(const float4*)&bias2[4 * tx];
        float4 bv1 = *(const float4*)&bias2[4 * tx + 64];
        float ba[8] = {bv0.x, bv0.y, bv0.z, bv0.w, bv1.x, bv1.y, bv1.z, bv1.w};
        #pragma unroll
        for (int i = 0; i < 2; ++i)
            #pragma unroll
            for (int j = 0; j < 4; ++j) {
                const int c = 4 * tx + 64 * i + j;
                float4 v;
                v.x = fmaxf(acc[0][i * 4 + j] + ba[i * 4 + j], 0.f);
                v.y = fmaxf(acc[1][i * 4 + j] + ba[i * 4 + j], 0.f);
                v.z = fmaxf(acc[2][i * 4 + j] + ba[i * 4 + j], 0.f);
                v.w = fmaxf(acc[3][i * 4 + j] + ba[i * 4 + j], 0.f);
                *(float4*)&T[TIDX(c, 4 * ty)] = v;
            }
    }
    __syncthreads();                        // H^T visible to all
    if (t < HIDD) S[t] = wsv[t];            // ph4 prep (ordered by post-ph3 barrier)

    // ---------------- phase 3: sims = H @ A_c (+cv_c), row argmin.
    // Two 128-col passes, acc[4][8]; T read-only, A from global -> no barriers.
    for (int cbk = 0; cbk < 3; ++cbk) {
        float mv[4] = {3.4e38f, 3.4e38f, 3.4e38f, 3.4e38f};
        int   mi[4] = {0, 0, 0, 0};
        #pragma unroll 1
        for (int half = 0; half < 2; ++half) {
            float acc[4][8] = {};
            const float* Ab = Amat + (size_t)cbk * HIDD * KCB + 128 * half + 4 * tx;
            #pragma unroll 4
            for (int k = 0; k < HIDD; ++k) {
                float4 a0 = *(const float4*)&T[TIDX(k, 4 * ty)];
                float4 b0 = *(const float4*)(Ab + (size_t)k * KCB);
                float4 b1 = *(const float4*)(Ab + (size_t)k * KCB + 64);
                float aa[4] = {a0.x, a0.y, a0.z, a0.w};
                float bb[8] = {b0.x, b0.y, b0.z, b0.w, b1.x, b1.y, b1.z, b1.w};
                #pragma unroll
                for (int r = 0; r < 4; ++r)
                    #pragma unroll
                    for (int j = 0; j < 8; ++j)
                        acc[r][j] = fmaf(aa[r], bb[j], acc[r][j]);
            }
            const float* cvb = cv + cbk * KCB + 128 * half + 4 * tx;
            float4 c0 = *(const float4*)cvb;
            float4 c1 = *(const float4*)(cvb + 64);
            float ca[8] = {c0.x, c0.y, c0.z, c0.w, c1.x, c1.y, c1.z, c1.w};
            // cols ascend within thread; pass0 (<128) precedes pass1 (>=128);
            // strict < keeps earliest index on ties.
            #pragma unroll
            for (int i = 0; i < 2; ++i)
                #pragma unroll
                for (int j = 0; j < 4; ++j) {
                    const int c = 128 * half + 64 * i + 4 * tx + j;
                    #pragma unroll
                    for (int r = 0; r < 4; ++r) {
                        float v = acc[r][4 * i + j] + ca[4 * i + j];
                        if (v < mv[r]) { mv[r] = v; mi[r] = c; }
                    }
                }
        }
        // reduce across the 16 tx-lanes sharing these 4 rows (same wave)
        #pragma unroll
        for (int d = 1; d < 16; d <<= 1) {
            #pragma unroll
            for (int r = 0; r < 4; ++r) {
                float ov = __shfl_xor(mv[r], d);
                int   oi = __shfl_xor(mi[r], d);
                if (ov < mv[r] || (ov == mv[r] && oi < mi[r])) { mv[r] = ov; mi[r] = oi; }
            }
        }
        if (tx == 0) {
            #pragma unroll
            for (int r = 0; r < 4; ++r)
                codes[(size_t)(row0 + 4 * ty + r) * 3 + cbk] = mi[r];
        }
    }

    // ---------------- phase 4: logits + global histogram of order keys
    __syncthreads();                        // S(wsv) visible
    if (t < RPB) {
        float s = 0.f;
        #pragma unroll 8
        for (int k = 0; k < HIDD; ++k) s = fmaf(T[TIDX(k, t)], S[k], s);
        logits[row0 + t] = s;
        atomicAdd(&hist[order_key(s) >> 16], 1u);
    }
}

// ---------------------------------------------------------------------------
// Find cutoff bin p: (# elements in bins > p) < 32 <= (# in bins >= p)
// ---------------------------------------------------------------------------
__global__ __launch_bounds__(1024) void vq_findp(const unsigned* __restrict__ hist,
                                                 unsigned* __restrict__ meta)
{
    __shared__ unsigned Tb[1024];
    __shared__ unsigned sIg, sPg;
    const int t = threadIdx.x;
    unsigned s = 0;
    const uint4* hv = (const uint4*)(hist + (size_t)t * 64);
    for (int j = 0; j < 16; ++j) { uint4 h = hv[j]; s += h.x + h.y + h.z + h.w; }
    Tb[t] = s;
    __syncthreads();
    for (int d = 1; d < 1024; d <<= 1) {           // inclusive suffix sum
        unsigned v = (t + d < 1024) ? Tb[t + d] : 0u;
        __syncthreads();
        Tb[t] += v;
        __syncthreads();
    }
    const unsigned Ti = Tb[t];
    const unsigned P  = Ti - s;
    if (P < 32u && Ti >= 32u) { sIg = (unsigned)t; sPg = P; }
    __syncthreads();
    const int ig = (int)sIg;
    const unsigned Pg = sPg;
    if (t < 64) {
        unsigned c = hist[ig * 64 + t];
        unsigned Tw = c;
        #pragma unroll
        for (int d = 1; d < 64; d <<= 1) {
            unsigned v = __shfl_down(Tw, d);
            if (t + d < 64) Tw += v;
        }
        unsigned Pl = Pg + Tw - c;
        if (Pl < 32u && Pl + c >= 32u) { meta[2] = (unsigned)(ig * 64 + t); meta[3] = Pl; }
    }
}

// ---------------------------------------------------------------------------
// Collect candidates: bin > p -> list A (all selected), bin == p -> list B
// ---------------------------------------------------------------------------
__global__ __launch_bounds__(256) void vq_collect(
    const float* __restrict__ logits, unsigned* __restrict__ meta,
    unsigned* __restrict__ listA, unsigned* __restrict__ listB)
{
    const int i = blockIdx.x * 256 + threadIdx.x;
    const unsigned key = order_key(logits[i]);
    const unsigned p = meta[2];
    const unsigned b = key >> 16;
    if (b > p) {
        unsigned idx = atomicAdd(&meta[0], 1u);
        if (idx < 64u) { listA[2 * idx] = key; listA[2 * idx + 1] = (unsigned)i; }
    } else if (b == p) {
        unsigned idx = atomicAdd(&meta[1], 1u);
        if (idx < LISTB_CAP) { listB[2 * idx] = key; listB[2 * idx + 1] = (unsigned)i; }
    }
}

// ---------------------------------------------------------------------------
// Parallel ordered selection of 32 (value desc, index asc — lax.top_k)
// ---------------------------------------------------------------------------
__global__ __launch_bounds__(256) void vq_final(
    const unsigned* __restrict__ meta,
    const unsigned* __restrict__ listA, const unsigned* __restrict__ listB,
    const int* __restrict__ codes,
    int* __restrict__ outki, int* __restrict__ outsel)
{
    __shared__ unsigned Ks[64 + LISTB_CAP];
    __shared__ unsigned Is[64 + LISTB_CAP];
    __shared__ int sel[32];
    const int t = threadIdx.x;
    const unsigned nAv = meta[0];
    const unsigned nBv = meta[1];
    const int nA = (nAv > 64u) ? 64 : (int)nAv;
    const int nB = (nBv > LISTB_CAP) ? (int)LISTB_CAP : (int)nBv;
    const int n  = nA + nB;
    for (int j = t; j < n; j += 256) {
        if (j < nA) { Ks[j] = listA[2 * j]; Is[j] = listA[2 * j + 1]; }
        else        { int jj = j - nA; Ks[j] = listB[2 * jj]; Is[j] = listB[2 * jj + 1]; }
    }
    __syncthreads();
    for (int j = t; j < n; j += 256) {
        const unsigned kj = Ks[j], ij = Is[j];
        int rank = 0;
        for (int m = 0; m < n; ++m) {
            const unsigned km = Ks[m], im = Is[m];
            rank += (km > kj) || (km == kj && im < ij);
        }
        if (rank < 32) sel[rank] = (int)ij;
    }
    __syncthreads();
    if (t < 32) outki[t] = sel[t];
    if (t < 96) outsel[t] = codes[3 * sel[t / 3] + (t % 3)];
}

// ---------------------------------------------------------------------------
extern "C" void kernel_launch(void* const* d_in, const int* in_sizes, int n_in,
                              void* d_out, int out_size, void* d_ws, size_t ws_size,
                              hipStream_t stream)
{
    (void)in_sizes; (void)n_in; (void)out_size; (void)ws_size;

    const float* h0  = (const float*)d_in[0];
    const float* W1  = (const float*)d_in[1];
    const float* b1  = (const float*)d_in[2];
    const float* W2  = (const float*)d_in[3];
    const float* b2  = (const float*)d_in[4];
    const float* Wm  = (const float*)d_in[5];
    const float* bm  = (const float*)d_in[6];
    const float* Wt  = (const float*)d_in[7];
    const float* bt  = (const float*)d_in[8];
    const float* Wp  = (const float*)d_in[9];
    const float* bp  = (const float*)d_in[10];
    const float* cbm = (const float*)d_in[11];
    const float* cbt = (const float*)d_in[12];
    const float* cbp = (const float*)d_in[13];
    const float* wsv = (const float*)d_in[14];

    float*    wsf   = (float*)d_ws;
    unsigned* wsu   = (unsigned*)d_ws;
    float*    A     = wsf + OFF_A;
    float*    cvv   = wsf + OFF_CV;
    float*    logit = wsf + OFF_LOG;
    unsigned* hist  = wsu + OFF_HIST;
    unsigned* meta  = wsu + OFF_META;
    unsigned* listA = wsu + OFF_LISTA;
    unsigned* listB = wsu + OFF_LISTB;

    int* codes  = (int*)d_out;
    int* outki  = codes + (size_t)NROWS * 3;
    int* outsel = outki + 32;

    vq_precompute<<<24, 256, 0, stream>>>(Wm, bm, Wt, bt, Wp, bp, cbm, cbt, cbp, A, cvv, hist);
    vq_main<<<NROWS / RPB, THREADS, 0, stream>>>(h0, W1, b1, W2, b2, A, cvv, wsv, codes, logit, hist);
    vq_findp<<<1, 1024, 0, stream>>>(hist, meta);
    vq_collect<<<NROWS / 256, 256, 0, stream>>>(logit, meta, listA, listB);
    vq_final<<<1, 256, 0, stream>>>(meta, listA, listB, codes, outki, outsel);
}

// Round 6
// 815.952 us; speedup vs baseline: 1.3493x; 1.3493x over previous
//
#include <hip/hip_runtime.h>

#define NROWS   131072
#define INDIM   512
#define HIDD    128
#define KCB     256
#define RPB     128   // rows per block
#define THREADS 256   // 4 waves: wave w owns a 32/64-col slice, lane r owns rows 2r,2r+1

// ---- d_ws layout (32-bit word offsets) ----
#define OFF_A     0u        // 3*128*256 = 98304 : folded codebook matrices
#define OFF_CV    98304u    // 3*256            : folded bias terms
#define OFF_LOG   99072u    // 131072           : logits
#define OFF_HIST  230144u   // 65536            : top-16-bit histogram
#define OFF_META  295680u   // 16               : cntA, cntB, p, Sp
#define OFF_LISTA 295696u   // 64*2
#define OFF_LISTB 295824u   // 2048*2
#define LISTB_CAP 2048u

__device__ __forceinline__ unsigned order_key(float f) {
    unsigned u = __float_as_uint(f);
    return u ^ ((u & 0x80000000u) ? 0xFFFFFFFFu : 0x80000000u);
}

// load 32 consecutive floats from a wave-uniform address -> SGPRs (s_load_dwordx16 x2)
#define SLOAD32(dst, ptr) do {                       \
    const float* p_ = (ptr);                         \
    _Pragma("unroll")                                \
    for (int j_ = 0; j_ < 32; ++j_) dst[j_] = p_[j_]; \
} while (0)

// 64 FMAs: VGPR rows x SGPR cols
#define FMA_STEP(av, sb) do {                                  \
    _Pragma("unroll")                                          \
    for (int j_ = 0; j_ < 32; ++j_) {                          \
        acc0[j_] = fmaf((av).x, sb[j_], acc0[j_]);             \
        acc1[j_] = fmaf((av).y, sb[j_], acc1[j_]);             \
    }                                                          \
} while (0)

// ---------------------------------------------------------------------------
// Precompute A_c[j][k] = (1/||cb_k||) * sum_d W_c[j][d]*cb_k[d]
//            cv_c[k]   = (1/||cb_k||) * sum_d  b_c[d]*cb_k[d]
// Also zeros hist+meta (stream-ordered before vq_main).
// ---------------------------------------------------------------------------
__global__ __launch_bounds__(256) void vq_precompute(
    const float* __restrict__ Wm, const float* __restrict__ bm,
    const float* __restrict__ Wt, const float* __restrict__ bt,
    const float* __restrict__ Wp, const float* __restrict__ bp,
    const float* __restrict__ cbm, const float* __restrict__ cbt, const float* __restrict__ cbp,
    float* __restrict__ A, float* __restrict__ cv, unsigned* __restrict__ hist)
{
    for (unsigned i = blockIdx.x * 256u + threadIdx.x; i < 65536u + 16u; i += 24u * 256u)
        hist[i] = 0u;

    const int c  = blockIdx.x >> 3;
    const int jg = (blockIdx.x & 7) * 16;
    const float* W  = (c == 0) ? Wm  : (c == 1) ? Wt  : Wp;
    const float* bb = (c == 0) ? bm  : (c == 1) ? bt  : bp;
    const float* cb = (c == 0) ? cbm : (c == 1) ? cbt : cbp;
    const int k = threadIdx.x;
    const float4* cbr = (const float4*)(cb + (size_t)k * HIDD);
    float s = 0.f;
    for (int d = 0; d < HIDD / 4; ++d) {
        float4 x = cbr[d];
        s += x.x * x.x + x.y * x.y + x.z * x.z + x.w * x.w;
    }
    const float rn = 1.f / fmaxf(sqrtf(s), 1e-12f);
    for (int j = jg; j < jg + 16; ++j) {
        const float4* wr = (const float4*)(W + (size_t)j * HIDD);
        float acc = 0.f;
        for (int d = 0; d < HIDD / 4; ++d) {
            float4 x = cbr[d]; float4 w = wr[d];
            acc += x.x * w.x + x.y * w.y + x.z * w.z + x.w * w.w;
        }
        A[((size_t)c * HIDD + j) * KCB + k] = acc * rn;
    }
    if (jg == 0) {
        const float4* br = (const float4*)bb;
        float acc = 0.f;
        for (int d = 0; d < HIDD / 4; ++d) {
            float4 x = cbr[d]; float4 w = br[d];
            acc += x.x * w.x + x.y * w.y + x.z * w.z + x.w * w.w;
        }
        cv[(size_t)c * KCB + k] = acc * rn;
    }
}

// ---------------------------------------------------------------------------
// Main fused kernel, scalar-broadcast GEMM layout:
//   wave w (of 4) owns a 32-wide column slice; lane r owns rows 2r, 2r+1.
//   B operands (W1/W2/A) are wave-uniform -> SGPRs via s_load (scalar pipe),
//   double-buffered 2-k deep. A-operand: one ds_read_b64 per k. Per wave per
//   k: 64 FMA vs 1 b64 + 2 s_loadx16 -> VALU-issue-bound by construction.
//   acc[2][32] = 64 VGPR -> no spills at any allocator budget.
// LDS: T 64K (h0-chunk staging aliases its first 8K during ph1) + 4.5K reduce
//   buffers -> 68.5 KiB -> 2 blocks/CU.
// ---------------------------------------------------------------------------
__global__ __launch_bounds__(THREADS) void vq_main(
    const float* __restrict__ h0, const float* __restrict__ W1, const float* __restrict__ bias1,
    const float* __restrict__ W2, const float* __restrict__ bias2,
    const float* __restrict__ Amat, const float* __restrict__ cv, const float* __restrict__ wsv,
    int* __restrict__ codes, float* __restrict__ logits, unsigned* __restrict__ hist)
{
    __shared__ float T[HIDD * RPB];     // 64 KiB [k][row]; first 8 KiB doubles as ph1 staging
    __shared__ float MVs[4 * RPB];      // per-wave argmin partial values
    __shared__ int   MIs[4 * RPB];      // per-wave argmin partial indices
    __shared__ float WS[HIDD];          // wsv copy for ph4

    const int t    = threadIdx.x;
    const int lane = t & 63;
    const int wid  = __builtin_amdgcn_readfirstlane(t >> 6);   // provably uniform
    const int r2   = 2 * lane;                                  // rows r2, r2+1
    const int row0 = blockIdx.x * RPB;
    float* St = T;                                              // ph1 staging alias (16k x 128)

    // ---------------- phase 1: a1 = relu(h0 @ W1 + b1) -> T (transposed)
    {
        const int cb = wid * 32;
        float acc0[32] = {}, acc1[32] = {};
        float sbA[32], sbB[32];
        const int srow = t >> 1;
        const int sq   = (t & 1) * 8;
        const float* hp = h0 + (size_t)(row0 + srow) * INDIM + sq;
        float4 ha = *(const float4*)(hp);
        float4 hb = *(const float4*)(hp + 4);
        for (int kc = 0; kc < INDIM; kc += 16) {
            __syncthreads();                       // prev chunk consumed
            St[(sq + 0) * RPB + srow] = ha.x;
            St[(sq + 1) * RPB + srow] = ha.y;
            St[(sq + 2) * RPB + srow] = ha.z;
            St[(sq + 3) * RPB + srow] = ha.w;
            St[(sq + 4) * RPB + srow] = hb.x;
            St[(sq + 5) * RPB + srow] = hb.y;
            St[(sq + 6) * RPB + srow] = hb.z;
            St[(sq + 7) * RPB + srow] = hb.w;
            if (kc + 16 < INDIM) {                 // prefetch next h0 chunk under compute
                ha = *(const float4*)(hp + kc + 16);
                hb = *(const float4*)(hp + kc + 20);
            }
            __syncthreads();                       // staging ready
            float2 aE = *(const float2*)&St[0 * RPB + r2];
            float2 aO = *(const float2*)&St[1 * RPB + r2];
            SLOAD32(sbA, W1 + (size_t)(kc + 0) * HIDD + cb);
            SLOAD32(sbB, W1 + (size_t)(kc + 1) * HIDD + cb);
            #pragma unroll 1
            for (int k2 = 0; k2 < 16; k2 += 2) {
                const int k2n = (k2 + 2) & 15;     // wraps: harmless reload on last iter
                float2 aE2 = *(const float2*)&St[k2n * RPB + r2];
                float2 aO2 = *(const float2*)&St[(k2n + 1) * RPB + r2];
                FMA_STEP(aE, sbA);
                SLOAD32(sbA, W1 + (size_t)(kc + k2n) * HIDD + cb);
                FMA_STEP(aO, sbB);
                SLOAD32(sbB, W1 + (size_t)(kc + k2n + 1) * HIDD + cb);
                aE = aE2; aO = aO2;
            }
        }
        __syncthreads();                           // last chunk reads done; St region reusable
        float sb0[32];
        SLOAD32(sb0, bias1 + cb);
        #pragma unroll
        for (int j = 0; j < 32; ++j) {
            float2 v;
            v.x = fmaxf(acc0[j] + sb0[j], 0.f);
            v.y = fmaxf(acc1[j] + sb0[j], 0.f);
            *(float2*)&T[(cb + j) * RPB + r2] = v;
        }
    }
    __syncthreads();

    // ---------------- phase 2: H = relu(a1 @ W2 + b2) -> T (in place, after barrier)
    {
        const int cb = wid * 32;
        float acc0[32] = {}, acc1[32] = {};
        float sbA[32], sbB[32];
        float2 aE = *(const float2*)&T[0 * RPB + r2];
        float2 aO = *(const float2*)&T[1 * RPB + r2];
        SLOAD32(sbA, W2 + cb);
        SLOAD32(sbB, W2 + HIDD + cb);
        #pragma unroll 1
        for (int k2 = 0; k2 < HIDD; k2 += 2) {
            const int k2n = (k2 + 2) & (HIDD - 1);
            float2 aE2 = *(const float2*)&T[k2n * RPB + r2];
            float2 aO2 = *(const float2*)&T[(k2n + 1) * RPB + r2];
            FMA_STEP(aE, sbA);
            SLOAD32(sbA, W2 + (size_t)k2n * HIDD + cb);
            FMA_STEP(aO, sbB);
            SLOAD32(sbB, W2 + (size_t)(k2n + 1) * HIDD + cb);
            aE = aE2; aO = aO2;
        }
        __syncthreads();                           // all a1 reads done before overwrite
        float sb0[32];
        SLOAD32(sb0, bias2 + cb);
        #pragma unroll
        for (int j = 0; j < 32; ++j) {
            float2 v;
            v.x = fmaxf(acc0[j] + sb0[j], 0.f);
            v.y = fmaxf(acc1[j] + sb0[j], 0.f);
            *(float2*)&T[(cb + j) * RPB + r2] = v;
        }
    }
    if (t < HIDD) WS[t] = wsv[t];                  // ph4 prep; visible after next barrier
    __syncthreads();                               // H^T ready

    // ---------------- phase 3: sims = H @ A_c (+cv_c), row argmin
    // wave w owns cols [64w, 64w+63] as two 32-col passes (ascending -> ties ok)
    for (int cbk = 0; cbk < 3; ++cbk) {
        float mv0 = 3.4e38f, mv1 = 3.4e38f;
        int   mi0 = 0, mi1 = 0;
        #pragma unroll 1
        for (int half = 0; half < 2; ++half) {
            const int cb = wid * 64 + half * 32;
            const float* Ab = Amat + (size_t)cbk * HIDD * KCB + cb;
            float acc0[32] = {}, acc1[32] = {};
            float sbA[32], sbB[32];
            float2 aE = *(const float2*)&T[0 * RPB + r2];
            float2 aO = *(const float2*)&T[1 * RPB + r2];
            SLOAD32(sbA, Ab);
            SLOAD32(sbB, Ab + KCB);
            #pragma unroll 1
            for (int k2 = 0; k2 < HIDD; k2 += 2) {
                const int k2n = (k2 + 2) & (HIDD - 1);
                float2 aE2 = *(const float2*)&T[k2n * RPB + r2];
                float2 aO2 = *(const float2*)&T[(k2n + 1) * RPB + r2];
                FMA_STEP(aE, sbA);
                SLOAD32(sbA, Ab + (size_t)k2n * KCB);
                FMA_STEP(aO, sbB);
                SLOAD32(sbB, Ab + (size_t)(k2n + 1) * KCB);
                aE = aE2; aO = aO2;
            }
            float sc[32];
            SLOAD32(sc, cv + cbk * KCB + cb);
            #pragma unroll
            for (int j = 0; j < 32; ++j) {         // cols ascend; strict < keeps earliest
                const int c = cb + j;
                float v0 = acc0[j] + sc[j];
                float v1 = acc1[j] + sc[j];
                if (v0 < mv0) { mv0 = v0; mi0 = c; }
                if (v1 < mv1) { mv1 = v1; mi1 = c; }
            }
        }
        // cross-wave combine: wave col-ranges ascend with wid
        MVs[wid * RPB + r2]     = mv0;  MIs[wid * RPB + r2]     = mi0;
        MVs[wid * RPB + r2 + 1] = mv1;  MIs[wid * RPB + r2 + 1] = mi1;
        __syncthreads();
        if (t < RPB) {
            float bv = MVs[t]; int bi = MIs[t];
            #pragma unroll
            for (int w = 1; w < 4; ++w) {
                float v = MVs[w * RPB + t]; int i2 = MIs[w * RPB + t];
                if (v < bv || (v == bv && i2 < bi)) { bv = v; bi = i2; }
            }
            codes[(size_t)(row0 + t) * 3 + cbk] = bi;
        }
        __syncthreads();                           // MVs/MIs reusable
    }

    // ---------------- phase 4: logits + global histogram of order keys
    if (t < RPB) {
        float s = 0.f;
        #pragma unroll 8
        for (int k = 0; k < HIDD; ++k) s = fmaf(T[k * RPB + t], WS[k], s);
        logits[row0 + t] = s;
        atomicAdd(&hist[order_key(s) >> 16], 1u);
    }
}

// ---------------------------------------------------------------------------
// Find cutoff bin p: (# elements in bins > p) < 32 <= (# in bins >= p)
// ---------------------------------------------------------------------------
__global__ __launch_bounds__(1024) void vq_findp(const unsigned* __restrict__ hist,
                                                 unsigned* __restrict__ meta)
{
    __shared__ unsigned Tb[1024];
    __shared__ unsigned sIg, sPg;
    const int t = threadIdx.x;
    unsigned s = 0;
    const uint4* hv = (const uint4*)(hist + (size_t)t * 64);
    for (int j = 0; j < 16; ++j) { uint4 h = hv[j]; s += h.x + h.y + h.z + h.w; }
    Tb[t] = s;
    __syncthreads();
    for (int d = 1; d < 1024; d <<= 1) {           // inclusive suffix sum
        unsigned v = (t + d < 1024) ? Tb[t + d] : 0u;
        __syncthreads();
        Tb[t] += v;
        __syncthreads();
    }
    const unsigned Ti = Tb[t];
    const unsigned P  = Ti - s;
    if (P < 32u && Ti >= 32u) { sIg = (unsigned)t; sPg = P; }
    __syncthreads();
    const int ig = (int)sIg;
    const unsigned Pg = sPg;
    if (t < 64) {
        unsigned c = hist[ig * 64 + t];
        unsigned Tw = c;
        #pragma unroll
        for (int d = 1; d < 64; d <<= 1) {
            unsigned v = __shfl_down(Tw, d);
            if (t + d < 64) Tw += v;
        }
        unsigned Pl = Pg + Tw - c;
        if (Pl < 32u && Pl + c >= 32u) { meta[2] = (unsigned)(ig * 64 + t); meta[3] = Pl; }
    }
}

// ---------------------------------------------------------------------------
// Collect candidates: bin > p -> list A (all selected), bin == p -> list B
// ---------------------------------------------------------------------------
__global__ __launch_bounds__(256) void vq_collect(
    const float* __restrict__ logits, unsigned* __restrict__ meta,
    unsigned* __restrict__ listA, unsigned* __restrict__ listB)
{
    const int i = blockIdx.x * 256 + threadIdx.x;
    const unsigned key = order_key(logits[i]);
    const unsigned p = meta[2];
    const unsigned b = key >> 16;
    if (b > p) {
        unsigned idx = atomicAdd(&meta[0], 1u);
        if (idx < 64u) { listA[2 * idx] = key; listA[2 * idx + 1] = (unsigned)i; }
    } else if (b == p) {
        unsigned idx = atomicAdd(&meta[1], 1u);
        if (idx < LISTB_CAP) { listB[2 * idx] = key; listB[2 * idx + 1] = (unsigned)i; }
    }
}

// ---------------------------------------------------------------------------
// Parallel ordered selection of 32 (value desc, index asc — lax.top_k)
// ---------------------------------------------------------------------------
__global__ __launch_bounds__(256) void vq_final(
    const unsigned* __restrict__ meta,
    const unsigned* __restrict__ listA, const unsigned* __restrict__ listB,
    const int* __restrict__ codes,
    int* __restrict__ outki, int* __restrict__ outsel)
{
    __shared__ unsigned Ks[64 + LISTB_CAP];
    __shared__ unsigned Is[64 + LISTB_CAP];
    __shared__ int sel[32];
    const int t = threadIdx.x;
    const unsigned nAv = meta[0];
    const unsigned nBv = meta[1];
    const int nA = (nAv > 64u) ? 64 : (int)nAv;
    const int nB = (nBv > LISTB_CAP) ? (int)LISTB_CAP : (int)nBv;
    const int n  = nA + nB;
    for (int j = t; j < n; j += 256) {
        if (j < nA) { Ks[j] = listA[2 * j]; Is[j] = listA[2 * j + 1]; }
        else        { int jj = j - nA; Ks[j] = listB[2 * jj]; Is[j] = listB[2 * jj + 1]; }
    }
    __syncthreads();
    for (int j = t; j < n; j += 256) {
        const unsigned kj = Ks[j], ij = Is[j];
        int rank = 0;
        for (int m = 0; m < n; ++m) {
            const unsigned km = Ks[m], im = Is[m];
            rank += (km > kj) || (km == kj && im < ij);
        }
        if (rank < 32) sel[rank] = (int)ij;
    }
    __syncthreads();
    if (t < 32) outki[t] = sel[t];
    if (t < 96) outsel[t] = codes[3 * sel[t / 3] + (t % 3)];
}

// ---------------------------------------------------------------------------
extern "C" void kernel_launch(void* const* d_in, const int* in_sizes, int n_in,
                              void* d_out, int out_size, void* d_ws, size_t ws_size,
                              hipStream_t stream)
{
    (void)in_sizes; (void)n_in; (void)out_size; (void)ws_size;

    const float* h0  = (const float*)d_in[0];
    const float* W1  = (const float*)d_in[1];
    const float* b1  = (const float*)d_in[2];
    const float* W2  = (const float*)d_in[3];
    const float* b2  = (const float*)d_in[4];
    const float* Wm  = (const float*)d_in[5];
    const float* bm  = (const float*)d_in[6];
    const float* Wt  = (const float*)d_in[7];
    const float* bt  = (const float*)d_in[8];
    const float* Wp  = (const float*)d_in[9];
    const float* bp  = (const float*)d_in[10];
    const float* cbm = (const float*)d_in[11];
    const float* cbt = (const float*)d_in[12];
    const float* cbp = (const float*)d_in[13];
    const float* wsv = (const float*)d_in[14];

    float*    wsf   = (float*)d_ws;
    unsigned* wsu   = (unsigned*)d_ws;
    float*    A     = wsf + OFF_A;
    float*    cvv   = wsf + OFF_CV;
    float*    logit = wsf + OFF_LOG;
    unsigned* hist  = wsu + OFF_HIST;
    unsigned* meta  = wsu + OFF_META;
    unsigned* listA = wsu + OFF_LISTA;
    unsigned* listB = wsu + OFF_LISTB;

    int* codes  = (int*)d_out;
    int* outki  = codes + (size_t)NROWS * 3;
    int* outsel = outki + 32;

    vq_precompute<<<24, 256, 0, stream>>>(Wm, bm, Wt, bt, Wp, bp, cbm, cbt, cbp, A, cvv, hist);
    vq_main<<<NROWS / RPB, THREADS, 0, stream>>>(h0, W1, b1, W2, b2, A, cvv, wsv, codes, logit, hist);
    vq_findp<<<1, 1024, 0, stream>>>(hist, meta);
    vq_collect<<<NROWS / 256, 256, 0, stream>>>(logit, meta, listA, listB);
    vq_final<<<1, 256, 0, stream>>>(meta, listA, listB, codes, outki, outsel);
}